// Round 15
// baseline (441.201 us; speedup 1.0000x reference)
//
#include <hip/hip_runtime.h>

#define B_  16
#define L_  4096
#define D_  128
#define NT  (L_ / 64)

typedef __attribute__((ext_vector_type(8)))  __bf16 bf16x8;
typedef __attribute__((ext_vector_type(2)))  __bf16 bf16x2;
typedef __attribute__((ext_vector_type(16))) float  f32x16;
typedef __attribute__((ext_vector_type(4)))  float  f32x4;
typedef __attribute__((ext_vector_type(4)))  int    i32x4;
typedef __attribute__((ext_vector_type(8)))  unsigned short u16x8;
typedef __attribute__((ext_vector_type(4)))  unsigned short u16x4;

#ifndef __has_builtin
#define __has_builtin(x) 0
#endif
#if __has_builtin(__builtin_amdgcn_permlane32_swap)
#define HAVE_PLSWAP 1
#else
#define HAVE_PLSWAP 0
#endif

__device__ __forceinline__ unsigned short f2bf(float f){
  unsigned u = __builtin_bit_cast(unsigned, f);
  u += 0x7fffu + ((u >> 16) & 1u);   // RNE
  return (unsigned short)(u >> 16);
}

__device__ __forceinline__ int packbf(float a, float b){
  bf16x2 t; t[0] = (__bf16)a; t[1] = (__bf16)b;
  return __builtin_bit_cast(int, t);
}

__device__ __forceinline__ void gload16(const void* g, void* l){
  __builtin_amdgcn_global_load_lds(
      (const __attribute__((address_space(1))) unsigned int*)g,
      (__attribute__((address_space(3))) unsigned int*)l, 16, 0, 0);
}

__device__ __forceinline__ f32x16 z16(){
  f32x16 t;
#pragma unroll
  for (int i = 0; i < 16; ++i) t[i] = 0.f;
  return t;
}

// ---- fp32 -> bf16 cast with scale (K: folds softmax temperature + log2e) ----
__global__ void cvt_bf16_kernel(const float* __restrict__ in,
                                unsigned short* __restrict__ out, int n8,
                                float scale){
  int i = blockIdx.x * blockDim.x + threadIdx.x;
  if (i >= n8) return;
  const float4* p = reinterpret_cast<const float4*>(in) + (size_t)i * 2;
  float4 a = p[0], b = p[1];
  u16x8 o;
  o[0]=f2bf(a.x*scale); o[1]=f2bf(a.y*scale); o[2]=f2bf(a.z*scale); o[3]=f2bf(a.w*scale);
  o[4]=f2bf(b.x*scale); o[5]=f2bf(b.y*scale); o[6]=f2bf(b.z*scale); o[7]=f2bf(b.w*scale);
  reinterpret_cast<u16x8*>(out)[i] = o;
}

// ---- V [B][L][D] fp32 -> Vt [B][D][L] bf16 ----
__global__ void transpose_v_kernel(const float* __restrict__ V,
                                   unsigned short* __restrict__ Vt){
  __shared__ unsigned short tile[64][65];
  const int k0 = blockIdx.x * 64, d0 = blockIdx.y * 64, b = blockIdx.z;
  const int tr = threadIdx.x >> 4, tc = threadIdx.x & 15;
  const float* src = V + ((size_t)b * L_ + k0) * D_ + d0;
#pragma unroll
  for (int p = 0; p < 4; ++p){
    int kl = p * 16 + tr;
    float4 v = *reinterpret_cast<const float4*>(src + (size_t)kl * D_ + tc * 4);
    tile[kl][tc*4+0] = f2bf(v.x);
    tile[kl][tc*4+1] = f2bf(v.y);
    tile[kl][tc*4+2] = f2bf(v.z);
    tile[kl][tc*4+3] = f2bf(v.w);
  }
  __syncthreads();
  unsigned short* dst = Vt + (size_t)b * D_ * L_ + (size_t)d0 * L_ + k0;
#pragma unroll
  for (int p = 0; p < 4; ++p){
    int dl = p * 16 + tr;
    u16x4 o;
    o[0] = tile[tc*4+0][dl];
    o[1] = tile[tc*4+1][dl];
    o[2] = tile[tc*4+2][dl];
    o[3] = tile[tc*4+3][dl];
    *reinterpret_cast<u16x4*>(dst + (size_t)dl * L_ + tc * 4) = o;
  }
}

// Build one PV A-operand chunk (16 keys) from per-lane P values.
__device__ __forceinline__ bf16x8 mkchunk(float a0,float a1,float a2,float a3,
                                          float a4,float a5,float a6,float a7,
                                          int hi){
  int x0 = packbf(a0,a1), x1 = packbf(a2,a3);
  int x2 = packbf(a4,a5), x3 = packbf(a6,a7);
  int W0, W1, W2, W3;
#if HAVE_PLSWAP
  {
    auto r = __builtin_amdgcn_permlane32_swap((unsigned)x0, (unsigned)x2, false, false);
    W0 = (int)r[0]; W2 = (int)r[1];
  }
  {
    auto r = __builtin_amdgcn_permlane32_swap((unsigned)x1, (unsigned)x3, false, false);
    W1 = (int)r[0]; W3 = (int)r[1];
  }
  (void)hi;
#else
  int y0 = __shfl_xor(x0, 32), y1 = __shfl_xor(x1, 32);
  int y2 = __shfl_xor(x2, 32), y3 = __shfl_xor(x3, 32);
  W0 = hi ? y2 : x0;  W1 = hi ? y3 : x1;
  W2 = hi ? x2 : y0;  W3 = hi ? x3 : y1;
#endif
  i32x4 ww; ww[0]=W0; ww[1]=W1; ww[2]=W2; ww[3]=W3;
  return __builtin_bit_cast(bf16x8, ww);
}

// ---- fused flash attention, round 15: K DIRECT global->VGPR (no K LDS).
// Rationale: r13 audit showed DS-read pipe (~3.1k cyc/tile/CU: all 8 waves
// re-read the full K+V tiles) exceeds MFMA demand (2.1k) -> LDS volume was
// the structural floor (~135us). K A-fragments are contiguous 16B chunks,
// identical addresses across waves -> L1-broadcast; DS now serves V only
// (~1.6k cyc/tile). r5's K-direct failure was scheduling: loads had no
// shadow work. Here per body: [issue 16 K-loads(i)] [SMPACK(i-1) VALU/TRANS
// shadows K latency] [interleaved QKT(i)+PV(i-1); vmcnt drains K only -- V
// prefetches are YOUNGER, never force-waited] [issue V(i+2) gload_lds]
// [barrier]. In-order vmcnt retirement makes cross-wave V guarantees free:
// V(i-1) is older than K(i-2), drained by every wave one barrier earlier.
// V LDS 4-deep (64KB), 16-slot swizzle (r11: conflict-free). Fixed-max
// softmax. 2 waves/SIMD (state ~240 VGPR; r12: 4/SIMD spills).
__global__ __launch_bounds__(512, 1)
void attn_kernel(const float* __restrict__ Q,
                 const unsigned short* __restrict__ Kb,   // bf16, pre-scaled
                 const unsigned short* __restrict__ Vt,   // bf16 V^T [B][D][L]
                 float* __restrict__ out){
  __shared__ char smem[65536];          // V^T 4 x 16KB
  char* Vlds = smem;

  const int tid = threadIdx.x;
  const int w = tid >> 6, l = tid & 63;
  const int row = l & 31, hi = l >> 5;
  const int swz = (row & 15) << 4;      // 16-slot swizzle (conflict-free, r11)
  const int b = blockIdx.x, qt = blockIdx.y;

  // Q fragments: lane holds Q[q = l&31][c*16 + hi*8 + j]; fp32->bf16 in-kernel
  const float* qptr = Q + ((size_t)b * L_ + (size_t)qt * 256 + w * 32 + row) * D_;
  bf16x8 qf[8];
#pragma unroll
  for (int c = 0; c < 8; ++c){
    float4 a  = *reinterpret_cast<const float4*>(qptr + c * 16 + hi * 8);
    float4 bb = *reinterpret_cast<const float4*>(qptr + c * 16 + hi * 8 + 4);
    u16x8 o;
    o[0]=f2bf(a.x);  o[1]=f2bf(a.y);  o[2]=f2bf(a.z);  o[3]=f2bf(a.w);
    o[4]=f2bf(bb.x); o[5]=f2bf(bb.y); o[6]=f2bf(bb.z); o[7]=f2bf(bb.w);
    qf[c] = __builtin_bit_cast(bf16x8, o);
  }

  const char* Kg = (const char*)(Kb + (size_t)b * L_ * D_);
  const char* Vg = (const char*)(Vt + (size_t)b * (size_t)D_ * L_);

  f32x16 o[4];
#pragma unroll
  for (int n = 0; n < 4; ++n) o[n] = z16();
  float ln = 0.f;   // per-lane partial (half keys); combined at epilogue

  // stage one 64-key V^T tile (16KB): rows packed (d, d+64) per 256B LDS row
  auto STAGE = [&](int bsel, int t){
    char* vd = Vlds + bsel * 16384;
    const int kv0 = t * 64;
#pragma unroll
    for (int j = 0; j < 2; ++j){
      int idx = j * 512 + tid;
      int lr = idx >> 4, sc = idx & 15;
      int clog = (sc << 4) ^ ((lr & 15) << 4);
      int dd = lr + ((clog >> 7) << 6);
      gload16(Vg + (size_t)dd * (L_ * 2) + (size_t)kv0 * 2 + (clog & 127),
              vd + idx * 16);
    }
  };

// Issue this tile's 16 K-fragment loads (global->VGPR, L1-broadcast across waves)
#define KLOAD(I)                                                               \
    const char* k0p_ = Kg + ((size_t)(I) * 64 + row) * 256 + hi * 16;          \
    bf16x8 kfa[8], kfb[8];                                                     \
    _Pragma("unroll")                                                          \
    for (int c = 0; c < 8; ++c) kfa[c] = *(const bf16x8*)(k0p_ + c * 32);      \
    _Pragma("unroll")                                                          \
    for (int c = 0; c < 8; ++c) kfb[c] = *(const bf16x8*)(k0p_ + 32*256 + c*32);

// Fixed-max softmax on (P0,P1) in-place -> pa0..3 in caller scope
#define SMPACK(P0, P1)                                                         \
    _Pragma("unroll")                                                          \
    for (int i2 = 0; i2 < 16; ++i2){                                           \
      P0[i2] = __builtin_amdgcn_exp2f(P0[i2]);                                 \
      P1[i2] = __builtin_amdgcn_exp2f(P1[i2]);                                 \
    }                                                                          \
    {                                                                          \
      f32x16 pt_ = P0 + P1;                                                    \
      float a0 = pt_[0]+pt_[1],  a1 = pt_[2]+pt_[3];                           \
      float a2 = pt_[4]+pt_[5],  a3 = pt_[6]+pt_[7];                           \
      float a4 = pt_[8]+pt_[9],  a5 = pt_[10]+pt_[11];                         \
      float a6 = pt_[12]+pt_[13], a7 = pt_[14]+pt_[15];                        \
      ln += ((a0+a1)+(a2+a3)) + ((a4+a5)+(a6+a7));                             \
    }                                                                          \
    bf16x8 pa0 = mkchunk(P0[0],P0[1],P0[2],P0[3],P0[4],P0[5],P0[6],P0[7], hi); \
    bf16x8 pa1 = mkchunk(P0[8],P0[9],P0[10],P0[11],P0[12],P0[13],P0[14],P0[15], hi); \
    bf16x8 pa2 = mkchunk(P1[0],P1[1],P1[2],P1[3],P1[4],P1[5],P1[6],P1[7], hi); \
    bf16x8 pa3 = mkchunk(P1[8],P1[9],P1[10],P1[11],P1[12],P1[13],P1[14],P1[15], hi);

// V fragment: d-row n*32+row -> lrow=(n&1)*32+row, col base (n>>1)*128
#define VF(VP, N, CH)                                                          \
  (*(const bf16x8*)((VP) + ((N & 1) * 32 + row) * 256 +                        \
                    ((((N >> 1) * 128) + (CH)*32 + hi*16) ^ swz)))

// Standalone PV from pa0..3 and V buffer VP (tail only)
#define PVONLY(VP)                                                             \
  {                                                                            \
    const char* Vp_ = (VP);                                                    \
    __builtin_amdgcn_s_setprio(1);                                             \
    _Pragma("unroll")                                                          \
    for (int n2 = 0; n2 < 4; ++n2){                                            \
      bf16x8 vf0 = VF(Vp_, n2, 0);                                             \
      bf16x8 vf1 = VF(Vp_, n2, 1);                                             \
      bf16x8 vf2 = VF(Vp_, n2, 2);                                             \
      bf16x8 vf3 = VF(Vp_, n2, 3);                                             \
      o[n2] = __builtin_amdgcn_mfma_f32_32x32x16_bf16(vf0, pa0, o[n2], 0,0,0); \
      o[n2] = __builtin_amdgcn_mfma_f32_32x32x16_bf16(vf1, pa1, o[n2], 0,0,0); \
      o[n2] = __builtin_amdgcn_mfma_f32_32x32x16_bf16(vf2, pa2, o[n2], 0,0,0); \
      o[n2] = __builtin_amdgcn_mfma_f32_32x32x16_bf16(vf3, pa3, o[n2], 0,0,0); \
    }                                                                          \
    __builtin_amdgcn_s_setprio(0);                                             \
  }

// body(i): [K loads i] [SMPACK(i-1) shadows K latency] [QKT(i) ∥ PV(i-1)]
//          [stage V(i+2)] [barrier]
#define BODY(I, C0, C1, P0, P1)                                                \
  {                                                                            \
    const int i_ = (I);                                                        \
    KLOAD(i_)                                                                  \
    SMPACK(P0, P1)                                                             \
    const char* Vp_ = Vlds + ((i_ - 1) & 3) * 16384;                           \
    C0 = z16(); C1 = z16();                                                    \
    __builtin_amdgcn_s_setprio(1);                                             \
    _Pragma("unroll")                                                          \
    for (int c = 0; c < 4; ++c){                                               \
      bf16x8 vf0 = VF(Vp_, c, 0);                                              \
      bf16x8 vf1 = VF(Vp_, c, 1);                                              \
      bf16x8 vf2 = VF(Vp_, c, 2);                                              \
      bf16x8 vf3 = VF(Vp_, c, 3);                                              \
      C0 = __builtin_amdgcn_mfma_f32_32x32x16_bf16(kfa[2*c],   qf[2*c],   C0, 0,0,0); \
      o[c] = __builtin_amdgcn_mfma_f32_32x32x16_bf16(vf0, pa0, o[c], 0,0,0);   \
      C1 = __builtin_amdgcn_mfma_f32_32x32x16_bf16(kfb[2*c],   qf[2*c],   C1, 0,0,0); \
      o[c] = __builtin_amdgcn_mfma_f32_32x32x16_bf16(vf1, pa1, o[c], 0,0,0);   \
      C0 = __builtin_amdgcn_mfma_f32_32x32x16_bf16(kfa[2*c+1], qf[2*c+1], C0, 0,0,0); \
      o[c] = __builtin_amdgcn_mfma_f32_32x32x16_bf16(vf2, pa2, o[c], 0,0,0);   \
      C1 = __builtin_amdgcn_mfma_f32_32x32x16_bf16(kfb[2*c+1], qf[2*c+1], C1, 0,0,0); \
      o[c] = __builtin_amdgcn_mfma_f32_32x32x16_bf16(vf3, pa3, o[c], 0,0,0);   \
    }                                                                          \
    __builtin_amdgcn_s_setprio(0);                                             \
    if (i_ + 2 < NT) STAGE((i_ + 2) & 3, i_ + 2);                              \
    __builtin_amdgcn_s_barrier();                                              \
  }

  // prologue: stage V tiles 0,1,2; hard drain so every wave's V(0..2) landed
  STAGE(0, 0); STAGE(1, 1); STAGE(2, 2);
  asm volatile("s_waitcnt vmcnt(0)" ::: "memory");
  __builtin_amdgcn_s_barrier();

  f32x16 sA0, sA1, sB0, sB1;
  {                                     // tile 0: QK^T only (K direct)
    KLOAD(0)
    sA0 = z16(); sA1 = z16();
    __builtin_amdgcn_s_setprio(1);
#pragma unroll
    for (int c = 0; c < 8; ++c){
      sA0 = __builtin_amdgcn_mfma_f32_32x32x16_bf16(kfa[c], qf[c], sA0, 0, 0, 0);
      sA1 = __builtin_amdgcn_mfma_f32_32x32x16_bf16(kfb[c], qf[c], sA1, 0, 0, 0);
    }
    __builtin_amdgcn_s_setprio(0);
  }

  for (int i = 1; i <= NT - 3; i += 2){ // bodies 1..62 (ping-pong sA/sB)
    BODY(i,     sB0, sB1, sA0, sA1);
    BODY(i + 1, sA0, sA1, sB0, sB1);
  }
  BODY(NT - 1, sB0, sB1, sA0, sA1);     // body 63
  { SMPACK(sB0, sB1) PVONLY(Vlds + ((NT - 1) & 3) * 16384); }  // tail

  // epilogue: combine lane-pair ln partials, normalize, store fp32
  float lt = ln + __shfl_xor(ln, 32);
  float inv = 1.0f / lt;
  float* outp = out + ((size_t)b * L_ + (size_t)qt * 256 + w * 32 + row) * D_;
#pragma unroll
  for (int n = 0; n < 4; ++n)
#pragma unroll
    for (int rq = 0; rq < 4; ++rq){
      f32x4 v4;
      v4[0] = o[n][rq*4+0] * inv;
      v4[1] = o[n][rq*4+1] * inv;
      v4[2] = o[n][rq*4+2] * inv;
      v4[3] = o[n][rq*4+3] * inv;
      *reinterpret_cast<f32x4*>(outp + n * 32 + rq * 8 + hi * 4) = v4;
    }
}

extern "C" void kernel_launch(void* const* d_in, const int* in_sizes, int n_in,
                              void* d_out, int out_size, void* d_ws, size_t ws_size,
                              hipStream_t stream){
  const float* Q = (const float*)d_in[0];
  const float* K = (const float*)d_in[1];
  const float* V = (const float*)d_in[2];
  float* out = (float*)d_out;

  const size_t NE = (size_t)B_ * L_ * D_;
  unsigned short* kb = (unsigned short*)d_ws;   // bf16 K*scale [B][L][D]
  unsigned short* vt = kb + NE;                 // bf16 V^T [B][D][L]

  const float SCALE_L2E = 1.4426950408889634f / 11.313708498984761f;
  int n8 = (int)(NE / 8);
  cvt_bf16_kernel<<<dim3(n8 / 256), 256, 0, stream>>>(K, kb, n8, SCALE_L2E);
  transpose_v_kernel<<<dim3(L_ / 64, D_ / 64, B_), 256, 0, stream>>>(V, vt);
  attn_kernel<<<dim3(B_, L_ / 256), 512, 0, stream>>>(Q, kb, vt, out);
}

// Round 16
// 168.894 us; speedup vs baseline: 2.6123x; 2.6123x over previous
//
#include <hip/hip_runtime.h>

#define B_  16
#define L_  4096
#define D_  128
#define NT  (L_ / 64)

typedef __attribute__((ext_vector_type(8)))  __bf16 bf16x8;
typedef __attribute__((ext_vector_type(2)))  __bf16 bf16x2;
typedef __attribute__((ext_vector_type(16))) float  f32x16;
typedef __attribute__((ext_vector_type(4)))  float  f32x4;
typedef __attribute__((ext_vector_type(4)))  int    i32x4;
typedef __attribute__((ext_vector_type(8)))  unsigned short u16x8;
typedef __attribute__((ext_vector_type(4)))  unsigned short u16x4;

#ifndef __has_builtin
#define __has_builtin(x) 0
#endif
#if __has_builtin(__builtin_amdgcn_permlane32_swap)
#define HAVE_PLSWAP 1
#else
#define HAVE_PLSWAP 0
#endif

__device__ __forceinline__ unsigned short f2bf(float f){
  unsigned u = __builtin_bit_cast(unsigned, f);
  u += 0x7fffu + ((u >> 16) & 1u);   // RNE
  return (unsigned short)(u >> 16);
}

__device__ __forceinline__ int packbf(float a, float b){
  bf16x2 t; t[0] = (__bf16)a; t[1] = (__bf16)b;
  return __builtin_bit_cast(int, t);
}

__device__ __forceinline__ void gload16(const void* g, void* l){
  __builtin_amdgcn_global_load_lds(
      (const __attribute__((address_space(1))) unsigned int*)g,
      (__attribute__((address_space(3))) unsigned int*)l, 16, 0, 0);
}

__device__ __forceinline__ f32x16 z16(){
  f32x16 t;
#pragma unroll
  for (int i = 0; i < 16; ++i) t[i] = 0.f;
  return t;
}

// ---- fp32 -> bf16 cast with scale (K: folds softmax temperature + log2e) ----
__global__ void cvt_bf16_kernel(const float* __restrict__ in,
                                unsigned short* __restrict__ out, int n8,
                                float scale){
  int i = blockIdx.x * blockDim.x + threadIdx.x;
  if (i >= n8) return;
  const float4* p = reinterpret_cast<const float4*>(in) + (size_t)i * 2;
  float4 a = p[0], b = p[1];
  u16x8 o;
  o[0]=f2bf(a.x*scale); o[1]=f2bf(a.y*scale); o[2]=f2bf(a.z*scale); o[3]=f2bf(a.w*scale);
  o[4]=f2bf(b.x*scale); o[5]=f2bf(b.y*scale); o[6]=f2bf(b.z*scale); o[7]=f2bf(b.w*scale);
  reinterpret_cast<u16x8*>(out)[i] = o;
}

// ---- V [B][L][D] fp32 -> Vt [B][D][L] bf16 ----
__global__ void transpose_v_kernel(const float* __restrict__ V,
                                   unsigned short* __restrict__ Vt){
  __shared__ unsigned short tile[64][65];
  const int k0 = blockIdx.x * 64, d0 = blockIdx.y * 64, b = blockIdx.z;
  const int tr = threadIdx.x >> 4, tc = threadIdx.x & 15;
  const float* src = V + ((size_t)b * L_ + k0) * D_ + d0;
#pragma unroll
  for (int p = 0; p < 4; ++p){
    int kl = p * 16 + tr;
    float4 v = *reinterpret_cast<const float4*>(src + (size_t)kl * D_ + tc * 4);
    tile[kl][tc*4+0] = f2bf(v.x);
    tile[kl][tc*4+1] = f2bf(v.y);
    tile[kl][tc*4+2] = f2bf(v.z);
    tile[kl][tc*4+3] = f2bf(v.w);
  }
  __syncthreads();
  unsigned short* dst = Vt + (size_t)b * D_ * L_ + (size_t)d0 * L_ + k0;
#pragma unroll
  for (int p = 0; p < 4; ++p){
    int dl = p * 16 + tr;
    u16x4 o;
    o[0] = tile[tc*4+0][dl];
    o[1] = tile[tc*4+1][dl];
    o[2] = tile[tc*4+2][dl];
    o[3] = tile[tc*4+3][dl];
    *reinterpret_cast<u16x4*>(dst + (size_t)dl * L_ + tc * 4) = o;
  }
}

// Build one PV A-operand chunk (16 keys) from per-lane P values.
__device__ __forceinline__ bf16x8 mkchunk(float a0,float a1,float a2,float a3,
                                          float a4,float a5,float a6,float a7,
                                          int hi){
  int x0 = packbf(a0,a1), x1 = packbf(a2,a3);
  int x2 = packbf(a4,a5), x3 = packbf(a6,a7);
  int W0, W1, W2, W3;
#if HAVE_PLSWAP
  {
    auto r = __builtin_amdgcn_permlane32_swap((unsigned)x0, (unsigned)x2, false, false);
    W0 = (int)r[0]; W2 = (int)r[1];
  }
  {
    auto r = __builtin_amdgcn_permlane32_swap((unsigned)x1, (unsigned)x3, false, false);
    W1 = (int)r[0]; W3 = (int)r[1];
  }
  (void)hi;
#else
  int y0 = __shfl_xor(x0, 32), y1 = __shfl_xor(x1, 32);
  int y2 = __shfl_xor(x2, 32), y3 = __shfl_xor(x3, 32);
  W0 = hi ? y2 : x0;  W1 = hi ? y3 : x1;
  W2 = hi ? x2 : y0;  W3 = hi ? x3 : y1;
#endif
  i32x4 ww; ww[0]=W0; ww[1]=W1; ww[2]=W2; ww[3]=W3;
  return __builtin_bit_cast(bf16x8, ww);
}

// ---- fused flash attention, round 16: r11 structure + intra-body
// instruction interleave. r11 audit: no pipe >40% busy (MFMA 2048, DS 2340,
// VALU 1740 of 6000 cyc/tile) -> intra-wave serialization is the limiter
// (in-order issue: serial SMPACK prefix idles MFMA pipe; serial 4-deep o[n]
// chains in PV). Changes, volumes untouched:
//  1. softmax(i-1) fused INTO QK^T(i) loop: each of 8 MFMA-pair iterations
//     carries a 4-exp+adds chunk -> VALU/TRANS issues in MFMA shadow.
//  2. PV chunk-outer: 4 reads + 4 MFMAs on 4 DIFFERENT o[n] (independent),
//     next mkchunk pack interleaved before each group.
//  3. C-init via loop-invariant ZERO operand (no 32 v_movs/tile).
// KVBLK=64, 4-deep buffers, 16-slot swizzle (conflict-free), fixed-max
// softmax, counted vmcnt(4) + raw barrier. 2 waves/SIMD (r12: more spills).
__global__ __launch_bounds__(512, 1)
void attn_kernel(const float* __restrict__ Q,
                 const unsigned short* __restrict__ Kb,   // bf16, pre-scaled
                 const unsigned short* __restrict__ Vt,   // bf16 V^T [B][D][L]
                 float* __restrict__ out){
  __shared__ char smem[131072];         // K 4x16KB | V^T 4x16KB
  char* Klds = smem;
  char* Vlds = smem + 65536;

  const int tid = threadIdx.x;
  const int w = tid >> 6, l = tid & 63;
  const int row = l & 31, hi = l >> 5;
  const int swz = (row & 15) << 4;      // 16-slot swizzle; rows r,r+32 share mask
  const int b = blockIdx.x, qt = blockIdx.y;

  // Q fragments: lane holds Q[q = l&31][c*16 + hi*8 + j]; fp32->bf16 in-kernel
  const float* qptr = Q + ((size_t)b * L_ + (size_t)qt * 256 + w * 32 + row) * D_;
  bf16x8 qf[8];
#pragma unroll
  for (int c = 0; c < 8; ++c){
    float4 a  = *reinterpret_cast<const float4*>(qptr + c * 16 + hi * 8);
    float4 bb = *reinterpret_cast<const float4*>(qptr + c * 16 + hi * 8 + 4);
    u16x8 o;
    o[0]=f2bf(a.x);  o[1]=f2bf(a.y);  o[2]=f2bf(a.z);  o[3]=f2bf(a.w);
    o[4]=f2bf(bb.x); o[5]=f2bf(bb.y); o[6]=f2bf(bb.z); o[7]=f2bf(bb.w);
    qf[c] = __builtin_bit_cast(bf16x8, o);
  }

  const char* Kg = (const char*)(Kb + (size_t)b * L_ * D_);
  const char* Vg = (const char*)(Vt + (size_t)b * (size_t)D_ * L_);

  f32x16 o[4];
#pragma unroll
  for (int n = 0; n < 4; ++n) o[n] = z16();
  const f32x16 ZERO = z16();            // loop-invariant MFMA C-operand
  float ln = 0.f;   // per-lane partial (half keys); combined at epilogue

  auto STAGE = [&](int bsel, int t){
    char* kd = Klds + bsel * 16384;
    char* vd = Vlds + bsel * 16384;
    const int kv0 = t * 64;
#pragma unroll
    for (int j = 0; j < 2; ++j){
      int idx = j * 512 + tid;
      int kr = idx >> 4, sc = idx & 15;
      int clog = (sc << 4) ^ ((kr & 15) << 4);
      gload16(Kg + (size_t)(kv0 + kr) * 256 + clog, kd + idx * 16);
    }
#pragma unroll
    for (int j = 0; j < 2; ++j){
      int idx = j * 512 + tid;
      int lr = idx >> 4, sc = idx & 15;
      int clog = (sc << 4) ^ ((lr & 15) << 4);
      int dd = lr + ((clog >> 7) << 6);   // V rows packed (d, d+64) per 256B row
      gload16(Vg + (size_t)dd * (L_ * 2) + (size_t)kv0 * 2 + (clog & 127),
              vd + idx * 16);
    }
  };

// softmax chunk: exp2 4 elems of P at J..J+3, accumulate ln
#define SMC(P, J)                                                              \
      P[(J)+0] = __builtin_amdgcn_exp2f(P[(J)+0]);                             \
      P[(J)+1] = __builtin_amdgcn_exp2f(P[(J)+1]);                             \
      P[(J)+2] = __builtin_amdgcn_exp2f(P[(J)+2]);                             \
      P[(J)+3] = __builtin_amdgcn_exp2f(P[(J)+3]);                             \
      ln += (P[(J)+0] + P[(J)+1]) + (P[(J)+2] + P[(J)+3]);

// K fragment pair for dword-chunk c
#define KF2(KC, C)                                                             \
      bf16x8 kf0 = *(const bf16x8*)((KC) + row * 256 + (((C)*32 + hi*16) ^ swz)); \
      bf16x8 kf1 = *(const bf16x8*)((KC) + (row+32) * 256 + (((C)*32 + hi*16) ^ swz));

// PV group G with pack PA: 4 reads + 4 MFMAs on independent o[n]
#define PVG(VP, G, PA)                                                         \
    {                                                                          \
      bf16x8 v0 = *(const bf16x8*)((VP) + (0*32 + row) * 256 + (((G)*32 + hi*16) ^ swz));          \
      bf16x8 v1 = *(const bf16x8*)((VP) + (1*32 + row) * 256 + (((G)*32 + hi*16) ^ swz));          \
      bf16x8 v2 = *(const bf16x8*)((VP) + (0*32 + row) * 256 + ((128 + (G)*32 + hi*16) ^ swz));    \
      bf16x8 v3 = *(const bf16x8*)((VP) + (1*32 + row) * 256 + ((128 + (G)*32 + hi*16) ^ swz));    \
      o[0] = __builtin_amdgcn_mfma_f32_32x32x16_bf16(v0, PA, o[0], 0, 0, 0);   \
      o[1] = __builtin_amdgcn_mfma_f32_32x32x16_bf16(v1, PA, o[1], 0, 0, 0);   \
      o[2] = __builtin_amdgcn_mfma_f32_32x32x16_bf16(v2, PA, o[2], 0, 0, 0);   \
      o[3] = __builtin_amdgcn_mfma_f32_32x32x16_bf16(v3, PA, o[3], 0, 0, 0);   \
    }

// PV block (4 groups), packs interleaved before each group
#define PVALL(VP, P0, P1)                                                      \
    bf16x8 pa0 = mkchunk(P0[0],P0[1],P0[2],P0[3],P0[4],P0[5],P0[6],P0[7], hi); \
    bf16x8 pa1 = mkchunk(P0[8],P0[9],P0[10],P0[11],P0[12],P0[13],P0[14],P0[15], hi); \
    PVG(Vp_, 0, pa0)                                                           \
    bf16x8 pa2 = mkchunk(P1[0],P1[1],P1[2],P1[3],P1[4],P1[5],P1[6],P1[7], hi); \
    PVG(Vp_, 1, pa1)                                                           \
    bf16x8 pa3 = mkchunk(P1[8],P1[9],P1[10],P1[11],P1[12],P1[13],P1[14],P1[15], hi); \
    PVG(Vp_, 2, pa2)                                                           \
    PVG(Vp_, 3, pa3)

// body(i): STAGE(i+2) | { QK^T(i) with softmax(i-1) chunks fused in } |
//          { PV(i-1), chunk-outer, packs interleaved } | vmcnt(4)+barrier
#define BODY(I, C0, C1, P0, P1)                                                \
  {                                                                            \
    const int i_ = (I);                                                        \
    if (i_ + 2 < NT) STAGE((i_ + 2) & 3, i_ + 2);                              \
    const char* Kc_ = Klds + (i_ & 3) * 16384;                                 \
    const char* Vp_ = Vlds + ((i_ - 1) & 3) * 16384;                           \
    __builtin_amdgcn_s_setprio(1);                                             \
    {   /* c = 0: C-init via ZERO operand */                                   \
      KF2(Kc_, 0)                                                              \
      C0 = __builtin_amdgcn_mfma_f32_32x32x16_bf16(kf0, qf[0], ZERO, 0, 0, 0); \
      C1 = __builtin_amdgcn_mfma_f32_32x32x16_bf16(kf1, qf[0], ZERO, 0, 0, 0); \
      SMC(P0, 0)                                                               \
    }                                                                          \
    _Pragma("unroll")                                                          \
    for (int c = 1; c < 8; ++c){                                               \
      KF2(Kc_, c)                                                              \
      C0 = __builtin_amdgcn_mfma_f32_32x32x16_bf16(kf0, qf[c], C0, 0, 0, 0);   \
      C1 = __builtin_amdgcn_mfma_f32_32x32x16_bf16(kf1, qf[c], C1, 0, 0, 0);   \
      if (c < 4) { SMC(P0, 4*c) } else { SMC(P1, 4*(c-4)) }                    \
    }                                                                          \
    PVALL(Vp_, P0, P1)                                                         \
    __builtin_amdgcn_s_setprio(0);                                             \
    if (i_ + 2 < NT) { asm volatile("s_waitcnt vmcnt(4)" ::: "memory"); }      \
    else             { asm volatile("s_waitcnt vmcnt(0)" ::: "memory"); }      \
    __builtin_amdgcn_s_barrier();                                              \
  }

  // prologue: stage tiles 0,1,2; guarantee tiles 0,1 landed (tile 2 in flight)
  STAGE(0, 0); STAGE(1, 1); STAGE(2, 2);
  asm volatile("s_waitcnt vmcnt(4)" ::: "memory");
  __builtin_amdgcn_s_barrier();

  f32x16 sA0, sA1, sB0, sB1;
  {                                     // tile 0: QK^T only
    const char* Kc_ = Klds;
    __builtin_amdgcn_s_setprio(1);
    {
      KF2(Kc_, 0)
      sA0 = __builtin_amdgcn_mfma_f32_32x32x16_bf16(kf0, qf[0], ZERO, 0, 0, 0);
      sA1 = __builtin_amdgcn_mfma_f32_32x32x16_bf16(kf1, qf[0], ZERO, 0, 0, 0);
    }
#pragma unroll
    for (int c = 1; c < 8; ++c){
      KF2(Kc_, c)
      sA0 = __builtin_amdgcn_mfma_f32_32x32x16_bf16(kf0, qf[c], sA0, 0, 0, 0);
      sA1 = __builtin_amdgcn_mfma_f32_32x32x16_bf16(kf1, qf[c], sA1, 0, 0, 0);
    }
    __builtin_amdgcn_s_setprio(0);
  }

  for (int i = 1; i <= NT - 3; i += 2){ // bodies 1..62 (ping-pong sA/sB)
    BODY(i,     sB0, sB1, sA0, sA1);
    BODY(i + 1, sA0, sA1, sB0, sB1);
  }
  BODY(NT - 1, sB0, sB1, sA0, sA1);     // body 63
  {                                     // tail: softmax+PV(63), plain order
    const char* Vp_ = Vlds + ((NT - 1) & 3) * 16384;
#pragma unroll
    for (int j = 0; j < 16; j += 4) { SMC(sB0, j) }
#pragma unroll
    for (int j = 0; j < 16; j += 4) { SMC(sB1, j) }
    __builtin_amdgcn_s_setprio(1);
    PVALL(Vp_, sB0, sB1)
    __builtin_amdgcn_s_setprio(0);
  }

  // epilogue: combine lane-pair ln partials, normalize, store fp32
  float lt = ln + __shfl_xor(ln, 32);
  float inv = 1.0f / lt;
  float* outp = out + ((size_t)b * L_ + (size_t)qt * 256 + w * 32 + row) * D_;
#pragma unroll
  for (int n = 0; n < 4; ++n)
#pragma unroll
    for (int rq = 0; rq < 4; ++rq){
      f32x4 v4;
      v4[0] = o[n][rq*4+0] * inv;
      v4[1] = o[n][rq*4+1] * inv;
      v4[2] = o[n][rq*4+2] * inv;
      v4[3] = o[n][rq*4+3] * inv;
      *reinterpret_cast<f32x4*>(outp + n * 32 + rq * 8 + hi * 4) = v4;
    }
}

extern "C" void kernel_launch(void* const* d_in, const int* in_sizes, int n_in,
                              void* d_out, int out_size, void* d_ws, size_t ws_size,
                              hipStream_t stream){
  const float* Q = (const float*)d_in[0];
  const float* K = (const float*)d_in[1];
  const float* V = (const float*)d_in[2];
  float* out = (float*)d_out;

  const size_t NE = (size_t)B_ * L_ * D_;
  unsigned short* kb = (unsigned short*)d_ws;   // bf16 K*scale [B][L][D]
  unsigned short* vt = kb + NE;                 // bf16 V^T [B][D][L]

  const float SCALE_L2E = 1.4426950408889634f / 11.313708498984761f;
  int n8 = (int)(NE / 8);
  cvt_bf16_kernel<<<dim3(n8 / 256), 256, 0, stream>>>(K, kb, n8, SCALE_L2E);
  transpose_v_kernel<<<dim3(L_ / 64, D_ / 64, B_), 256, 0, stream>>>(V, vt);
  attn_kernel<<<dim3(B_, L_ / 256), 512, 0, stream>>>(Q, kb, vt, out);
}